// Round 3
// baseline (5361.496 us; speedup 1.0000x reference)
//
#include <hip/hip_runtime.h>
#include <hip/hip_cooperative_groups.h>

namespace cg = cooperative_groups;

// Problem constants (Network_29197187678952)
#define NN 50000          // nodes
#define NE 1600000        // edges
#define NB 8              // batch
#define NT 80             // timesteps
#define TN ((size_t)NT * NN)   // stride between batches in x/out: 4,000,000
#define DT_F 0.02f

#define LPN 2             // lanes (threads) per node in the fused kernel
#define REG_E 24          // register-cached edges per thread (covers <=48 edges/node)

// ---------------------------------------------------------------------------
// Setup kernels (rebuilt every call).
// ---------------------------------------------------------------------------

__global__ void init_nodes_kernel(const float* __restrict__ bias,
                                  const float* __restrict__ tc,
                                  float* __restrict__ v0,
                                  float* __restrict__ alpha,
                                  int* __restrict__ cnt) {
  int n = blockIdx.x * blockDim.x + threadIdx.x;
  if (n >= NN) return;
  float b = bias[n];
#pragma unroll
  for (int j = 0; j < NB; ++j) v0[(size_t)n * NB + j] = b;
  alpha[n] = DT_F / fmaxf(tc[n], DT_F);
  cnt[n] = 0;
}

__global__ void hist_kernel(const int* __restrict__ tgt, int* __restrict__ cnt) {
  int e = blockIdx.x * blockDim.x + threadIdx.x;
  if (e >= NE) return;
  atomicAdd(&cnt[tgt[e]], 1);
}

// Single-block chunked exclusive scan over NN counts (one pass over data).
#define SCAN_T 1024
#define SCAN_CHUNK 49      // 1024*49 = 50176 >= NN
__global__ __launch_bounds__(SCAN_T) void scan_kernel(int* __restrict__ cnt,
                                                      int* __restrict__ row_ptr) {
  __shared__ int buf[2][SCAN_T];
  const int tid = threadIdx.x;
  const int base = tid * SCAN_CHUNK;
  int s = 0;
  for (int k = 0; k < SCAN_CHUNK; ++k) {
    int i = base + k;
    if (i < NN) s += cnt[i];
  }
  int sel = 0;
  buf[0][tid] = s;
  __syncthreads();
#pragma unroll
  for (int off = 1; off < SCAN_T; off <<= 1) {
    int v = buf[sel][tid];
    if (tid >= off) v += buf[sel][tid - off];
    buf[sel ^ 1][tid] = v;
    sel ^= 1;
    __syncthreads();
  }
  int excl = buf[sel][tid] - s;
  int run = excl;
  for (int k = 0; k < SCAN_CHUNK; ++k) {
    int i = base + k;
    if (i < NN) {
      int c = cnt[i];
      row_ptr[i] = run;
      cnt[i] = run;  // becomes fill cursor
      run += c;
    }
  }
  if (tid == SCAN_T - 1) row_ptr[NN] = run;
}

// Scatter edges into CSR-by-target order; fuse static edge weight.
// Packed entry: {src_byte_offset, weight_bits} -> single 8B store.
__global__ void fill_kernel(const int* __restrict__ src, const int* __restrict__ tgt,
                            const float* __restrict__ sgn, const float* __restrict__ syn_cnt,
                            const float* __restrict__ syn_str,
                            int* __restrict__ cursor,
                            int2* __restrict__ csr) {
  int e = blockIdx.x * blockDim.x + threadIdx.x;
  if (e >= NE) return;
  int t = tgt[e];
  float w = sgn[e] * syn_cnt[e] * fmaxf(syn_str[e], 0.f);
  int pos = atomicAdd(&cursor[t], 1);
  csr[pos] = make_int2(src[e] * (NB * 4), __float_as_int(w));
}

// ---------------------------------------------------------------------------
// Fused all-timesteps cooperative kernel (primary path).
// 2 threads per node; each thread register-caches up to REG_E edges once,
// then runs all NT steps with grid.sync() between steps.
// v state node-major (N,8): one edge gather = contiguous 32B (2x float4).
// ---------------------------------------------------------------------------
__global__ __launch_bounds__(256, 2) void steps_kernel(
    const int* __restrict__ row_ptr,
    const int2* __restrict__ csr,
    float* v_a, float* v_b,                     // ping-pong state (no restrict!)
    const float* __restrict__ x,
    const float* __restrict__ bias,
    const float* __restrict__ alpha,
    float* __restrict__ out) {
  cg::grid_group grid = cg::this_grid();

  const int gid = blockIdx.x * blockDim.x + threadIdx.x;
  const int node = gid >> 1;
  const int lane = gid & 1;
  const bool active = node < NN;

  int e0 = 0, e1 = 0;
  float a = 0.f, bs = 0.f;
  if (active) {
    e0 = row_ptr[node];
    e1 = row_ptr[node + 1];
    a = alpha[node];
    bs = bias[node];
  }

  // register-cached edges: thread owns e0+lane, e0+lane+2, ...
  int rem = e1 - (e0 + lane);
  int nmine = rem > 0 ? ((rem + LPN - 1) >> 1) : 0;
  if (nmine > REG_E) nmine = REG_E;

  int soff[REG_E];
  float w[REG_E];
#pragma unroll
  for (int k = 0; k < REG_E; ++k) {
    int e = e0 + lane + k * LPN;
    if (e < e1) {
      int2 c = csr[e];
      soff[k] = c.x;
      w[k] = __int_as_float(c.y);
    } else {
      soff[k] = 0;
      w[k] = 0.f;
    }
  }
  const int eov0 = e0 + lane + REG_E * LPN;  // overflow start (rare, ~0.3% nodes)

  const float* vin = v_a;
  float* vout = v_b;
  const float* xp = x;
  float* op = out;
  // this thread finalizes batches lane*4 .. lane*4+3
  const size_t nb_off = (size_t)node * NB + lane * 4;
  const size_t b_base = (size_t)(lane * 4) * TN + node;

  for (int t = 0; t < NT; ++t) {
    float acc0 = 0.f, acc1 = 0.f, acc2 = 0.f, acc3 = 0.f;
    float acc4 = 0.f, acc5 = 0.f, acc6 = 0.f, acc7 = 0.f;

#pragma unroll
    for (int k = 0; k < REG_E; ++k) {
      if (k < nmine) {
        const float4* vp = (const float4*)((const char*)vin + soff[k]);
        float4 va = vp[0];
        float4 vb = vp[1];
        float wk = w[k];
        acc0 += wk * fmaxf(va.x, 0.f);
        acc1 += wk * fmaxf(va.y, 0.f);
        acc2 += wk * fmaxf(va.z, 0.f);
        acc3 += wk * fmaxf(va.w, 0.f);
        acc4 += wk * fmaxf(vb.x, 0.f);
        acc5 += wk * fmaxf(vb.y, 0.f);
        acc6 += wk * fmaxf(vb.z, 0.f);
        acc7 += wk * fmaxf(vb.w, 0.f);
      }
    }
    for (int e = eov0; e < e1; e += LPN) {  // overflow edges (rare)
      int2 c = csr[e];
      const float4* vp = (const float4*)((const char*)vin + c.x);
      float4 va = vp[0];
      float4 vb = vp[1];
      float wk = __int_as_float(c.y);
      acc0 += wk * fmaxf(va.x, 0.f);
      acc1 += wk * fmaxf(va.y, 0.f);
      acc2 += wk * fmaxf(va.z, 0.f);
      acc3 += wk * fmaxf(va.w, 0.f);
      acc4 += wk * fmaxf(vb.x, 0.f);
      acc5 += wk * fmaxf(vb.y, 0.f);
      acc6 += wk * fmaxf(vb.z, 0.f);
      acc7 += wk * fmaxf(vb.w, 0.f);
    }

    // pair reduce: lane 0 keeps batches 0-3, lane 1 keeps batches 4-7
    float k0 = lane ? acc4 : acc0, s0 = lane ? acc0 : acc4;
    float k1 = lane ? acc5 : acc1, s1 = lane ? acc1 : acc5;
    float k2 = lane ? acc6 : acc2, s2 = lane ? acc2 : acc6;
    float k3 = lane ? acc7 : acc3, s3 = lane ? acc3 : acc7;
    float r0 = k0 + __shfl_xor(s0, 1);
    float r1 = k1 + __shfl_xor(s1, 1);
    float r2 = k2 + __shfl_xor(s2, 1);
    float r3 = k3 + __shfl_xor(s3, 1);

    if (active) {
      float4 vo = *(const float4*)(vin + nb_off);
      float x0 = xp[b_base];
      float x1 = xp[b_base + TN];
      float x2 = xp[b_base + 2 * TN];
      float x3 = xp[b_base + 3 * TN];
      float4 vn;
      vn.x = vo.x + a * (bs - vo.x + r0 + x0);
      vn.y = vo.y + a * (bs - vo.y + r1 + x1);
      vn.z = vo.z + a * (bs - vo.z + r2 + x2);
      vn.w = vo.w + a * (bs - vo.w + r3 + x3);
      *(float4*)(vout + nb_off) = vn;
      op[b_base] = vn.x;
      op[b_base + TN] = vn.y;
      op[b_base + 2 * TN] = vn.z;
      op[b_base + 3 * TN] = vn.w;
    }

    if (t != NT - 1) grid.sync();

    const float* tv = vin;
    vin = vout;
    vout = (float*)tv;
    xp += NN;
    op += NN;
  }
}

// ---------------------------------------------------------------------------
// Fallback: single-timestep kernel (80 launches) if cooperative launch fails.
// Same decomposition (2 lanes/node), csr re-read each step.
// ---------------------------------------------------------------------------
__global__ __launch_bounds__(256) void step1_kernel(
    const int* __restrict__ row_ptr,
    const int2* __restrict__ csr,
    const float* __restrict__ v_old,
    float* __restrict__ v_new,
    const float* __restrict__ x_t,
    const float* __restrict__ bias,
    const float* __restrict__ alpha,
    float* __restrict__ out_t) {
  int gid = blockIdx.x * blockDim.x + threadIdx.x;
  int node = gid >> 1;
  int lane = gid & 1;
  if (node >= NN) return;

  int e0 = row_ptr[node];
  int e1 = row_ptr[node + 1];

  float acc0 = 0.f, acc1 = 0.f, acc2 = 0.f, acc3 = 0.f;
  float acc4 = 0.f, acc5 = 0.f, acc6 = 0.f, acc7 = 0.f;
  for (int e = e0 + lane; e < e1; e += LPN) {
    int2 c = csr[e];
    const float4* vp = (const float4*)((const char*)v_old + c.x);
    float4 va = vp[0];
    float4 vb = vp[1];
    float wk = __int_as_float(c.y);
    acc0 += wk * fmaxf(va.x, 0.f);
    acc1 += wk * fmaxf(va.y, 0.f);
    acc2 += wk * fmaxf(va.z, 0.f);
    acc3 += wk * fmaxf(va.w, 0.f);
    acc4 += wk * fmaxf(vb.x, 0.f);
    acc5 += wk * fmaxf(vb.y, 0.f);
    acc6 += wk * fmaxf(vb.z, 0.f);
    acc7 += wk * fmaxf(vb.w, 0.f);
  }

  float k0 = lane ? acc4 : acc0, s0 = lane ? acc0 : acc4;
  float k1 = lane ? acc5 : acc1, s1 = lane ? acc1 : acc5;
  float k2 = lane ? acc6 : acc2, s2 = lane ? acc2 : acc6;
  float k3 = lane ? acc7 : acc3, s3 = lane ? acc3 : acc7;
  float r0 = k0 + __shfl_xor(s0, 1);
  float r1 = k1 + __shfl_xor(s1, 1);
  float r2 = k2 + __shfl_xor(s2, 1);
  float r3 = k3 + __shfl_xor(s3, 1);

  size_t nb_off = (size_t)node * NB + lane * 4;
  size_t b_base = (size_t)(lane * 4) * TN + node;
  float a = alpha[node];
  float bs = bias[node];
  float4 vo = *(const float4*)(v_old + nb_off);
  float x0 = x_t[b_base];
  float x1 = x_t[b_base + TN];
  float x2 = x_t[b_base + 2 * TN];
  float x3 = x_t[b_base + 3 * TN];
  float4 vn;
  vn.x = vo.x + a * (bs - vo.x + r0 + x0);
  vn.y = vo.y + a * (bs - vo.y + r1 + x1);
  vn.z = vo.z + a * (bs - vo.z + r2 + x2);
  vn.w = vo.w + a * (bs - vo.w + r3 + x3);
  *(float4*)(v_new + nb_off) = vn;
  out_t[b_base] = vn.x;
  out_t[b_base + TN] = vn.y;
  out_t[b_base + 2 * TN] = vn.z;
  out_t[b_base + 3 * TN] = vn.w;
}

// ---------------------------------------------------------------------------

extern "C" void kernel_launch(void* const* d_in, const int* in_sizes, int n_in,
                              void* d_out, int out_size, void* d_ws, size_t ws_size,
                              hipStream_t stream) {
  const float* x        = (const float*)d_in[0];
  const float* bias     = (const float*)d_in[1];
  const float* tc       = (const float*)d_in[2];
  const float* sgn      = (const float*)d_in[3];
  const float* syn_cnt  = (const float*)d_in[4];
  const float* syn_str  = (const float*)d_in[5];
  const int*   src      = (const int*)d_in[6];
  const int*   tgt      = (const int*)d_in[7];
  float* out = (float*)d_out;

  // Workspace carve-out (~16.6 MB)
  char* p = (char*)d_ws;
  auto take = [&p](size_t bytes) {
    char* r = p;
    p += (bytes + 255) & ~(size_t)255;
    return (void*)r;
  };
  float* v_a     = (float*)take((size_t)NN * NB * sizeof(float));
  float* v_b     = (float*)take((size_t)NN * NB * sizeof(float));
  float* alpha   = (float*)take((size_t)NN * sizeof(float));
  int*   row_ptr = (int*)take(((size_t)NN + 1) * sizeof(int));
  int*   cursor  = (int*)take((size_t)NN * sizeof(int));
  int2*  csr     = (int2*)take((size_t)NE * sizeof(int2));

  // Build CSR-by-target + node params (once per call)
  init_nodes_kernel<<<(NN + 255) / 256, 256, 0, stream>>>(bias, tc, v_a, alpha, cursor);
  hist_kernel<<<(NE + 255) / 256, 256, 0, stream>>>(tgt, cursor);
  scan_kernel<<<1, SCAN_T, 0, stream>>>(cursor, row_ptr);
  fill_kernel<<<(NE + 255) / 256, 256, 0, stream>>>(src, tgt, sgn, syn_cnt, syn_str,
                                                    cursor, csr);

  // Primary: all 80 steps in one cooperative kernel.
  // 100,096 threads (2/node) in 391 blocks of 256; worst case occupancy at
  // <=256 VGPR is 2 blocks/CU -> capacity 512 >= 391.
  const int total_threads = NN * LPN;
  const int blocks = (total_threads + 255) / 256;
  void* args[] = {(void*)&row_ptr, (void*)&csr, (void*)&v_a, (void*)&v_b,
                  (void*)&x, (void*)&bias, (void*)&alpha, (void*)&out};
  hipError_t err = hipLaunchCooperativeKernel((void*)steps_kernel, dim3(blocks),
                                              dim3(256), args, 0, stream);

  if (err != hipSuccess) {
    // Fallback: 80 sequential step launches (proven-correct structure).
    const float* vin = v_a;
    float* vout = v_b;
    for (int t = 0; t < NT; ++t) {
      step1_kernel<<<blocks, 256, 0, stream>>>(
          row_ptr, csr, vin, vout,
          x + (size_t)t * NN, bias, alpha, out + (size_t)t * NN);
      float* tmp = (float*)vin;
      vin = vout;
      vout = tmp;
    }
  }
}

// Round 4
// 1366.353 us; speedup vs baseline: 3.9239x; 3.9239x over previous
//
#include <hip/hip_runtime.h>
#include <hip/hip_bf16.h>

// Problem constants (Network_29197187678952)
#define NN 50000          // nodes
#define NE 1600000        // edges
#define NB 8              // batch
#define NT 80             // timesteps
#define TN ((size_t)NT * NN)   // stride between batches in x/out: 4,000,000
#define DT_F 0.02f

#define LPN 8             // lanes (threads) per node in the step kernel

// ---------------------------------------------------------------------------
// Setup kernels (rebuilt every call).
// ---------------------------------------------------------------------------

// v0 = bias (fp32, node-major (N,8)); r0 = bf16(relu(bias)) gather state;
// alpha = dt/max(tau,dt); cnt = 0.
__global__ void init_nodes_kernel(const float* __restrict__ bias,
                                  const float* __restrict__ tc,
                                  float* __restrict__ v0,
                                  ushort* __restrict__ r0,
                                  float* __restrict__ alpha,
                                  int* __restrict__ cnt) {
  int n = blockIdx.x * blockDim.x + threadIdx.x;
  if (n >= NN) return;
  float b = bias[n];
  __hip_bfloat16 rb = __float2bfloat16(fmaxf(b, 0.f));
  ushort rbu = *(ushort*)&rb;
#pragma unroll
  for (int j = 0; j < NB; ++j) {
    v0[(size_t)n * NB + j] = b;
    r0[(size_t)n * NB + j] = rbu;
  }
  alpha[n] = DT_F / fmaxf(tc[n], DT_F);
  cnt[n] = 0;
}

__global__ void hist_kernel(const int* __restrict__ tgt, int* __restrict__ cnt) {
  int e = blockIdx.x * blockDim.x + threadIdx.x;
  if (e >= NE) return;
  atomicAdd(&cnt[tgt[e]], 1);
}

// Single-block chunked exclusive scan over NN counts (one pass over data).
#define SCAN_T 1024
#define SCAN_CHUNK 49      // 1024*49 = 50176 >= NN
__global__ __launch_bounds__(SCAN_T) void scan_kernel(int* __restrict__ cnt,
                                                      int* __restrict__ row_ptr) {
  __shared__ int buf[2][SCAN_T];
  const int tid = threadIdx.x;
  const int base = tid * SCAN_CHUNK;
  int s = 0;
  for (int k = 0; k < SCAN_CHUNK; ++k) {
    int i = base + k;
    if (i < NN) s += cnt[i];
  }
  int sel = 0;
  buf[0][tid] = s;
  __syncthreads();
#pragma unroll
  for (int off = 1; off < SCAN_T; off <<= 1) {
    int v = buf[sel][tid];
    if (tid >= off) v += buf[sel][tid - off];
    buf[sel ^ 1][tid] = v;
    sel ^= 1;
    __syncthreads();
  }
  int excl = buf[sel][tid] - s;
  int run = excl;
  for (int k = 0; k < SCAN_CHUNK; ++k) {
    int i = base + k;
    if (i < NN) {
      int c = cnt[i];
      row_ptr[i] = run;
      cnt[i] = run;  // becomes fill cursor
      run += c;
    }
  }
  if (tid == SCAN_T - 1) row_ptr[NN] = run;
}

// Scatter edges into CSR-by-target order; fuse static edge weight.
// Packed entry: {src_byte_offset_into_bf16x8_state, weight_bits} -> one 8B store.
__global__ void fill_kernel(const int* __restrict__ src, const int* __restrict__ tgt,
                            const float* __restrict__ sgn, const float* __restrict__ syn_cnt,
                            const float* __restrict__ syn_str,
                            int* __restrict__ cursor,
                            int2* __restrict__ csr) {
  int e = blockIdx.x * blockDim.x + threadIdx.x;
  if (e >= NE) return;
  int t = tgt[e];
  float w = sgn[e] * syn_cnt[e] * fmaxf(syn_str[e], 0.f);
  int pos = atomicAdd(&cursor[t], 1);
  csr[pos] = make_int2(src[e] * (NB * 2), __float_as_int(w));  // bf16x8 row = 16B
}

// ---------------------------------------------------------------------------
// Per-timestep fused kernel. 8 lanes per node (lane == batch):
//   - each lane strides the node's edge list, gathering pre-relu'd bf16x8
//     source state (16B per edge) and accumulating all 8 batches;
//   - 3-stage butterfly reduce across the 8-lane group;
//   - lane b finalizes batch b: Euler update, store v (fp32), relu-v (bf16),
//     and the output slice.
// ---------------------------------------------------------------------------
__global__ __launch_bounds__(256) void step1_kernel(
    const int* __restrict__ row_ptr,
    const int2* __restrict__ csr,
    const float* __restrict__ v_old,
    const ushort* __restrict__ r_old,   // bf16 relu state, node-major (N,8)
    float* __restrict__ v_new,
    ushort* __restrict__ r_new,
    const float* __restrict__ x_t,      // x + t*NN; batch stride TN
    const float* __restrict__ bias,
    const float* __restrict__ alpha,
    float* __restrict__ out_t) {        // out + t*NN; batch stride TN
  int gid = blockIdx.x * blockDim.x + threadIdx.x;
  int node = gid >> 3;
  int lane = gid & 7;
  if (node >= NN) return;

  int e0 = row_ptr[node];
  int e1 = row_ptr[node + 1];

  float acc[NB];
#pragma unroll
  for (int j = 0; j < NB; ++j) acc[j] = 0.f;

  for (int e = e0 + lane; e < e1; e += LPN) {
    int2 c = csr[e];
    uint4 rv = *(const uint4*)((const char*)r_old + c.x);  // 8x bf16, pre-relu'd
    float wk = __int_as_float(c.y);
    acc[0] += wk * __uint_as_float(rv.x << 16);
    acc[1] += wk * __uint_as_float(rv.x & 0xffff0000u);
    acc[2] += wk * __uint_as_float(rv.y << 16);
    acc[3] += wk * __uint_as_float(rv.y & 0xffff0000u);
    acc[4] += wk * __uint_as_float(rv.z << 16);
    acc[5] += wk * __uint_as_float(rv.z & 0xffff0000u);
    acc[6] += wk * __uint_as_float(rv.w << 16);
    acc[7] += wk * __uint_as_float(rv.w & 0xffff0000u);
  }

  // butterfly reduce across the 8-lane group; lane l ends with valid acc[l]
#pragma unroll
  for (int off = 4; off; off >>= 1) {
#pragma unroll
    for (int j = 0; j < NB; ++j) {
      float t = __shfl_xor(acc[j], off);
      acc[j] = (((lane ^ j) & off) == 0) ? acc[j] + t : acc[j];
    }
  }
  float r = acc[0];
#pragma unroll
  for (int j = 1; j < NB; ++j) r = (lane == j) ? acc[j] : r;

  float a = alpha[node];
  float bs = bias[node];
  size_t idx = (size_t)node * NB + lane;
  size_t boff = (size_t)lane * TN + node;
  float v = v_old[idx];
  float xv = x_t[boff];
  float vn = v + a * (bs - v + r + xv);
  v_new[idx] = vn;
  __hip_bfloat16 rh = __float2bfloat16(fmaxf(vn, 0.f));
  r_new[idx] = *(ushort*)&rh;
  out_t[boff] = vn;
}

// ---------------------------------------------------------------------------

extern "C" void kernel_launch(void* const* d_in, const int* in_sizes, int n_in,
                              void* d_out, int out_size, void* d_ws, size_t ws_size,
                              hipStream_t stream) {
  const float* x        = (const float*)d_in[0];
  const float* bias     = (const float*)d_in[1];
  const float* tc       = (const float*)d_in[2];
  const float* sgn      = (const float*)d_in[3];
  const float* syn_cnt  = (const float*)d_in[4];
  const float* syn_str  = (const float*)d_in[5];
  const int*   src      = (const int*)d_in[6];
  const int*   tgt      = (const int*)d_in[7];
  float* out = (float*)d_out;

  // Workspace carve-out (~18 MB)
  char* p = (char*)d_ws;
  auto take = [&p](size_t bytes) {
    char* r = p;
    p += (bytes + 255) & ~(size_t)255;
    return (void*)r;
  };
  float*  v_a     = (float*)take((size_t)NN * NB * sizeof(float));
  float*  v_b     = (float*)take((size_t)NN * NB * sizeof(float));
  ushort* r_a     = (ushort*)take((size_t)NN * NB * sizeof(ushort));
  ushort* r_b     = (ushort*)take((size_t)NN * NB * sizeof(ushort));
  float*  alpha   = (float*)take((size_t)NN * sizeof(float));
  int*    row_ptr = (int*)take(((size_t)NN + 1) * sizeof(int));
  int*    cursor  = (int*)take((size_t)NN * sizeof(int));
  int2*   csr     = (int2*)take((size_t)NE * sizeof(int2));

  // Build CSR-by-target + node params (once per call)
  init_nodes_kernel<<<(NN + 255) / 256, 256, 0, stream>>>(bias, tc, v_a, r_a, alpha, cursor);
  hist_kernel<<<(NE + 255) / 256, 256, 0, stream>>>(tgt, cursor);
  scan_kernel<<<1, SCAN_T, 0, stream>>>(cursor, row_ptr);
  fill_kernel<<<(NE + 255) / 256, 256, 0, stream>>>(src, tgt, sgn, syn_cnt, syn_str,
                                                    cursor, csr);

  // Sequential Euler steps; 8 lanes/node, 400K threads, plain launches.
  const int blocks = (NN * LPN + 255) / 256;
  const float* vin = v_a;
  float* vout = v_b;
  const ushort* rin = r_a;
  ushort* rout = r_b;
  for (int t = 0; t < NT; ++t) {
    step1_kernel<<<blocks, 256, 0, stream>>>(
        row_ptr, csr, vin, rin, vout, rout,
        x + (size_t)t * NN, bias, alpha, out + (size_t)t * NN);
    float* tv = (float*)vin; vin = vout; vout = tv;
    ushort* tr = (ushort*)rin; rin = rout; rout = tr;
  }
}

// Round 5
// 1201.447 us; speedup vs baseline: 4.4625x; 1.1373x over previous
//
#include <hip/hip_runtime.h>
#include <hip/hip_bf16.h>

// Problem constants (Network_29197187678952)
#define NN 50000          // nodes
#define NE 1600000        // edges
#define NB 8              // batch
#define NT 80             // timesteps
#define TN ((size_t)NT * NN)   // stride between batches in x/out: 4,000,000
#define DT_F 0.02f

#define LPN 8             // lanes (threads) per node in the step kernel
#define KPRE 8            // prefetched edges per lane (covers deg <= 64)

// ---------------------------------------------------------------------------
// Setup kernels (rebuilt every call).
// ---------------------------------------------------------------------------

__global__ void init_nodes_kernel(const float* __restrict__ bias,
                                  const float* __restrict__ tc,
                                  float* __restrict__ v0,
                                  ushort* __restrict__ r0,
                                  float* __restrict__ alpha,
                                  int* __restrict__ cnt) {
  int n = blockIdx.x * blockDim.x + threadIdx.x;
  if (n >= NN) return;
  float b = bias[n];
  __hip_bfloat16 rb = __float2bfloat16(fmaxf(b, 0.f));
  ushort rbu = *(ushort*)&rb;
#pragma unroll
  for (int j = 0; j < NB; ++j) {
    v0[(size_t)n * NB + j] = b;
    r0[(size_t)n * NB + j] = rbu;
  }
  alpha[n] = DT_F / fmaxf(tc[n], DT_F);
  cnt[n] = 0;
}

__global__ void hist_kernel(const int* __restrict__ tgt, int* __restrict__ cnt) {
  int e = blockIdx.x * blockDim.x + threadIdx.x;
  if (e >= NE) return;
  atomicAdd(&cnt[tgt[e]], 1);
}

// --- hierarchical 3-phase scan over NN counts (parallel, latency-friendly) ---
#define SCAN_BS 256
#define SCAN_NB ((NN + SCAN_BS - 1) / SCAN_BS)   // 196 blocks

// Phase 1: per-block exclusive scan -> escan; block totals -> partials.
__global__ __launch_bounds__(SCAN_BS) void scan1_kernel(
    const int* __restrict__ cnt, int* __restrict__ escan,
    int* __restrict__ partials) {
  __shared__ int buf[2][SCAN_BS];
  const int tid = threadIdx.x;
  const int i = blockIdx.x * SCAN_BS + tid;
  int v = (i < NN) ? cnt[i] : 0;
  int sel = 0;
  buf[0][tid] = v;
  __syncthreads();
#pragma unroll
  for (int off = 1; off < SCAN_BS; off <<= 1) {
    int s = buf[sel][tid];
    if (tid >= off) s += buf[sel][tid - off];
    buf[sel ^ 1][tid] = s;
    sel ^= 1;
    __syncthreads();
  }
  int incl = buf[sel][tid];
  if (i < NN) escan[i] = incl - v;
  if (tid == SCAN_BS - 1) partials[blockIdx.x] = incl;
}

// Phase 2: single-block scan of the 196 partials -> exclusive bases; total -> row_ptr[NN].
__global__ __launch_bounds__(SCAN_BS) void scan2_kernel(
    int* __restrict__ partials, int* __restrict__ row_ptr) {
  __shared__ int buf[2][SCAN_BS];
  const int tid = threadIdx.x;
  int v = (tid < SCAN_NB) ? partials[tid] : 0;
  int sel = 0;
  buf[0][tid] = v;
  __syncthreads();
#pragma unroll
  for (int off = 1; off < SCAN_BS; off <<= 1) {
    int s = buf[sel][tid];
    if (tid >= off) s += buf[sel][tid - off];
    buf[sel ^ 1][tid] = s;
    sel ^= 1;
    __syncthreads();
  }
  int incl = buf[sel][tid];
  if (tid < SCAN_NB) partials[tid] = incl - v;     // exclusive base per block
  if (tid == SCAN_BS - 1) row_ptr[NN] = incl;      // grand total (== NE)
}

// Phase 3: row_ptr[i] = cursor[i] = escan[i] + base[block].
__global__ __launch_bounds__(SCAN_BS) void scan3_kernel(
    const int* __restrict__ escan, const int* __restrict__ partials,
    int* __restrict__ row_ptr, int* __restrict__ cursor) {
  const int i = blockIdx.x * SCAN_BS + threadIdx.x;
  if (i >= NN) return;
  int r = escan[i] + partials[blockIdx.x];
  row_ptr[i] = r;
  cursor[i] = r;
}

// Scatter edges into CSR-by-target order; fuse static edge weight.
// Packed entry: {src_byte_offset_into_bf16x8_state, weight_bits} -> one 8B store.
__global__ void fill_kernel(const int* __restrict__ src, const int* __restrict__ tgt,
                            const float* __restrict__ sgn, const float* __restrict__ syn_cnt,
                            const float* __restrict__ syn_str,
                            int* __restrict__ cursor,
                            int2* __restrict__ csr) {
  int e = blockIdx.x * blockDim.x + threadIdx.x;
  if (e >= NE) return;
  int t = tgt[e];
  float w = sgn[e] * syn_cnt[e] * fmaxf(syn_str[e], 0.f);
  int pos = atomicAdd(&cursor[t], 1);
  csr[pos] = make_int2(src[e] * (NB * 2), __float_as_int(w));  // bf16x8 row = 16B
}

// ---------------------------------------------------------------------------
// Per-timestep fused kernel. 8 lanes per node (lane == batch).
// Latency fix: all KPRE CSR entries prefetched as independent loads, then all
// KPRE 16B gathers issued independently (inactive slots -> offset 0, w=0).
// Dependent chain: 1 csr latency + 1 gather latency instead of ~4x both.
// ---------------------------------------------------------------------------
__global__ __launch_bounds__(256) void step1_kernel(
    const int* __restrict__ row_ptr,
    const int2* __restrict__ csr,
    const float* __restrict__ v_old,
    const ushort* __restrict__ r_old,   // bf16 relu state, node-major (N,8)
    float* __restrict__ v_new,
    ushort* __restrict__ r_new,
    const float* __restrict__ x_t,      // x + t*NN; batch stride TN
    const float* __restrict__ bias,
    const float* __restrict__ alpha,
    float* __restrict__ out_t) {        // out + t*NN; batch stride TN
  int gid = blockIdx.x * blockDim.x + threadIdx.x;
  int node = gid >> 3;
  int lane = gid & 7;
  if (node >= NN) return;

  int e0 = row_ptr[node];
  int e1 = row_ptr[node + 1];
  int mybase = e0 + lane;
  int rem = e1 - mybase;
  int cnt = rem > 0 ? ((rem + LPN - 1) >> 3) : 0;   // my edge count (stride 8)

  // node-state loads independent of the edge chain — issue early
  float a = alpha[node];
  float bs = bias[node];
  size_t idx = (size_t)node * NB + lane;
  size_t boff = (size_t)lane * TN + node;
  float v = v_old[idx];
  float xv = x_t[boff];

  // prefetch CSR entries (independent loads)
  int soff[KPRE];
  float wk[KPRE];
#pragma unroll
  for (int k = 0; k < KPRE; ++k) {
    int2 c = (k < cnt) ? csr[mybase + (k << 3)] : make_int2(0, 0);
    soff[k] = c.x;
    wk[k] = __int_as_float(c.y);
  }

  // independent gathers (slot 0 of state for inactive -> w=0 contribution)
  uint4 rv[KPRE];
#pragma unroll
  for (int k = 0; k < KPRE; ++k)
    rv[k] = *(const uint4*)((const char*)r_old + soff[k]);

  float acc[NB];
#pragma unroll
  for (int j = 0; j < NB; ++j) acc[j] = 0.f;

#pragma unroll
  for (int k = 0; k < KPRE; ++k) {
    float w = wk[k];
    acc[0] += w * __uint_as_float(rv[k].x << 16);
    acc[1] += w * __uint_as_float(rv[k].x & 0xffff0000u);
    acc[2] += w * __uint_as_float(rv[k].y << 16);
    acc[3] += w * __uint_as_float(rv[k].y & 0xffff0000u);
    acc[4] += w * __uint_as_float(rv[k].z << 16);
    acc[5] += w * __uint_as_float(rv[k].z & 0xffff0000u);
    acc[6] += w * __uint_as_float(rv[k].w << 16);
    acc[7] += w * __uint_as_float(rv[k].w & 0xffff0000u);
  }

  // overflow edges (deg > 64; essentially never at Poisson(32))
  for (int e = mybase + (KPRE << 3); e < e1; e += LPN) {
    int2 c = csr[e];
    uint4 r8 = *(const uint4*)((const char*)r_old + c.x);
    float w = __int_as_float(c.y);
    acc[0] += w * __uint_as_float(r8.x << 16);
    acc[1] += w * __uint_as_float(r8.x & 0xffff0000u);
    acc[2] += w * __uint_as_float(r8.y << 16);
    acc[3] += w * __uint_as_float(r8.y & 0xffff0000u);
    acc[4] += w * __uint_as_float(r8.z << 16);
    acc[5] += w * __uint_as_float(r8.z & 0xffff0000u);
    acc[6] += w * __uint_as_float(r8.w << 16);
    acc[7] += w * __uint_as_float(r8.w & 0xffff0000u);
  }

  // butterfly reduce across the 8-lane group; lane l ends with valid acc[l]
#pragma unroll
  for (int off = 4; off; off >>= 1) {
#pragma unroll
    for (int j = 0; j < NB; ++j) {
      float t = __shfl_xor(acc[j], off);
      acc[j] = (((lane ^ j) & off) == 0) ? acc[j] + t : acc[j];
    }
  }
  float r = acc[0];
#pragma unroll
  for (int j = 1; j < NB; ++j) r = (lane == j) ? acc[j] : r;

  float vn = v + a * (bs - v + r + xv);
  v_new[idx] = vn;
  __hip_bfloat16 rh = __float2bfloat16(fmaxf(vn, 0.f));
  r_new[idx] = *(ushort*)&rh;
  out_t[boff] = vn;
}

// ---------------------------------------------------------------------------

extern "C" void kernel_launch(void* const* d_in, const int* in_sizes, int n_in,
                              void* d_out, int out_size, void* d_ws, size_t ws_size,
                              hipStream_t stream) {
  const float* x        = (const float*)d_in[0];
  const float* bias     = (const float*)d_in[1];
  const float* tc       = (const float*)d_in[2];
  const float* sgn      = (const float*)d_in[3];
  const float* syn_cnt  = (const float*)d_in[4];
  const float* syn_str  = (const float*)d_in[5];
  const int*   src      = (const int*)d_in[6];
  const int*   tgt      = (const int*)d_in[7];
  float* out = (float*)d_out;

  // Workspace carve-out (~19 MB)
  char* p = (char*)d_ws;
  auto take = [&p](size_t bytes) {
    char* r = p;
    p += (bytes + 255) & ~(size_t)255;
    return (void*)r;
  };
  float*  v_a      = (float*)take((size_t)NN * NB * sizeof(float));
  float*  v_b      = (float*)take((size_t)NN * NB * sizeof(float));
  ushort* r_a      = (ushort*)take((size_t)NN * NB * sizeof(ushort));
  ushort* r_b      = (ushort*)take((size_t)NN * NB * sizeof(ushort));
  float*  alpha    = (float*)take((size_t)NN * sizeof(float));
  int*    row_ptr  = (int*)take(((size_t)NN + 1) * sizeof(int));
  int*    cnt      = (int*)take((size_t)NN * sizeof(int));
  int*    cursor   = (int*)take((size_t)NN * sizeof(int));
  int*    escan    = (int*)take((size_t)NN * sizeof(int));
  int*    partials = (int*)take((size_t)SCAN_NB * sizeof(int));
  int2*   csr      = (int2*)take((size_t)NE * sizeof(int2));

  // Build CSR-by-target + node params (once per call)
  init_nodes_kernel<<<(NN + 255) / 256, 256, 0, stream>>>(bias, tc, v_a, r_a, alpha, cnt);
  hist_kernel<<<(NE + 255) / 256, 256, 0, stream>>>(tgt, cnt);
  scan1_kernel<<<SCAN_NB, SCAN_BS, 0, stream>>>(cnt, escan, partials);
  scan2_kernel<<<1, SCAN_BS, 0, stream>>>(partials, row_ptr);
  scan3_kernel<<<SCAN_NB, SCAN_BS, 0, stream>>>(escan, partials, row_ptr, cursor);
  fill_kernel<<<(NE + 255) / 256, 256, 0, stream>>>(src, tgt, sgn, syn_cnt, syn_str,
                                                    cursor, csr);

  // Sequential Euler steps; 8 lanes/node, 400K threads, plain launches.
  const int blocks = (NN * LPN + 255) / 256;
  const float* vin = v_a;
  float* vout = v_b;
  const ushort* rin = r_a;
  ushort* rout = r_b;
  for (int t = 0; t < NT; ++t) {
    step1_kernel<<<blocks, 256, 0, stream>>>(
        row_ptr, csr, vin, rin, vout, rout,
        x + (size_t)t * NN, bias, alpha, out + (size_t)t * NN);
    float* tv = (float*)vin; vin = vout; vout = tv;
    ushort* tr = (ushort*)rin; rin = rout; rout = tr;
  }
}

// Round 6
// 1179.292 us; speedup vs baseline: 4.5464x; 1.0188x over previous
//
#include <hip/hip_runtime.h>
#include <hip/hip_bf16.h>

// Problem constants (Network_29197187678952)
#define NN 50000          // nodes
#define NE 1600000        // edges
#define NB 8              // batch
#define NT 80             // timesteps
#define TN ((size_t)NT * NN)   // stride between batches in x/out: 4,000,000
#define DT_F 0.02f

#define LPN 8             // lanes (threads) per node in the step kernel
#define KPRE 8            // prefetched edges per lane (covers deg <= 64)

// ---------------------------------------------------------------------------
// Setup kernels (rebuilt every call).
// ---------------------------------------------------------------------------

__global__ void init_nodes_kernel(const float* __restrict__ bias,
                                  const float* __restrict__ tc,
                                  float* __restrict__ v0,
                                  ushort* __restrict__ r0,
                                  float* __restrict__ alpha,
                                  int* __restrict__ cnt) {
  int n = blockIdx.x * blockDim.x + threadIdx.x;
  if (n >= NN) return;
  float b = bias[n];
  __hip_bfloat16 rb = __float2bfloat16(fmaxf(b, 0.f));
  ushort rbu = *(ushort*)&rb;
#pragma unroll
  for (int j = 0; j < NB; ++j) {
    v0[(size_t)n * NB + j] = b;
    r0[(size_t)n * NB + j] = rbu;
  }
  alpha[n] = DT_F / fmaxf(tc[n], DT_F);
  cnt[n] = 0;
}

__global__ void hist_kernel(const int* __restrict__ tgt, int* __restrict__ cnt) {
  int e = blockIdx.x * blockDim.x + threadIdx.x;
  if (e >= NE) return;
  atomicAdd(&cnt[tgt[e]], 1);
}

// --- hierarchical 3-phase scan over NN counts ---
#define SCAN_BS 256
#define SCAN_NB ((NN + SCAN_BS - 1) / SCAN_BS)   // 196 blocks

__global__ __launch_bounds__(SCAN_BS) void scan1_kernel(
    const int* __restrict__ cnt, int* __restrict__ escan,
    int* __restrict__ partials) {
  __shared__ int buf[2][SCAN_BS];
  const int tid = threadIdx.x;
  const int i = blockIdx.x * SCAN_BS + tid;
  int v = (i < NN) ? cnt[i] : 0;
  int sel = 0;
  buf[0][tid] = v;
  __syncthreads();
#pragma unroll
  for (int off = 1; off < SCAN_BS; off <<= 1) {
    int s = buf[sel][tid];
    if (tid >= off) s += buf[sel][tid - off];
    buf[sel ^ 1][tid] = s;
    sel ^= 1;
    __syncthreads();
  }
  int incl = buf[sel][tid];
  if (i < NN) escan[i] = incl - v;
  if (tid == SCAN_BS - 1) partials[blockIdx.x] = incl;
}

__global__ __launch_bounds__(SCAN_BS) void scan2_kernel(
    int* __restrict__ partials, int* __restrict__ row_ptr) {
  __shared__ int buf[2][SCAN_BS];
  const int tid = threadIdx.x;
  int v = (tid < SCAN_NB) ? partials[tid] : 0;
  int sel = 0;
  buf[0][tid] = v;
  __syncthreads();
#pragma unroll
  for (int off = 1; off < SCAN_BS; off <<= 1) {
    int s = buf[sel][tid];
    if (tid >= off) s += buf[sel][tid - off];
    buf[sel ^ 1][tid] = s;
    sel ^= 1;
    __syncthreads();
  }
  int incl = buf[sel][tid];
  if (tid < SCAN_NB) partials[tid] = incl - v;     // exclusive base per block
  if (tid == SCAN_BS - 1) row_ptr[NN] = incl;      // grand total (== NE)
}

__global__ __launch_bounds__(SCAN_BS) void scan3_kernel(
    const int* __restrict__ escan, const int* __restrict__ partials,
    int* __restrict__ row_ptr, int* __restrict__ cursor) {
  const int i = blockIdx.x * SCAN_BS + threadIdx.x;
  if (i >= NN) return;
  int r = escan[i] + partials[blockIdx.x];
  row_ptr[i] = r;
  cursor[i] = r;
}

// Scatter edges into CSR-by-target order; fuse static edge weight.
__global__ void fill_kernel(const int* __restrict__ src, const int* __restrict__ tgt,
                            const float* __restrict__ sgn, const float* __restrict__ syn_cnt,
                            const float* __restrict__ syn_str,
                            int* __restrict__ cursor,
                            int2* __restrict__ csr) {
  int e = blockIdx.x * blockDim.x + threadIdx.x;
  if (e >= NE) return;
  int t = tgt[e];
  float w = sgn[e] * syn_cnt[e] * fmaxf(syn_str[e], 0.f);
  int pos = atomicAdd(&cursor[t], 1);
  csr[pos] = make_int2(src[e] * (NB * 2), __float_as_int(w));  // bf16x8 row = 16B
}

// ---------------------------------------------------------------------------
// Per-timestep fused kernel. 8 lanes per node (lane == batch).
// KPRE independent CSR loads, then KPRE *predicated* independent gathers —
// exec-masked inactive slots issue no TA line requests (the dummy-gather
// traffic was ~half of all requests). rv explicitly zeroed when inactive
// (w=0 * NaN-garbage would poison acc).
// x load / out store are non-temporal: streaming read-once/write-once, keep
// them from evicting csr + r-state from L2.
// ---------------------------------------------------------------------------
__global__ __launch_bounds__(256) void step1_kernel(
    const int* __restrict__ row_ptr,
    const int2* __restrict__ csr,
    const float* __restrict__ v_old,
    const ushort* __restrict__ r_old,   // bf16 relu state, node-major (N,8)
    float* __restrict__ v_new,
    ushort* __restrict__ r_new,
    const float* __restrict__ x_t,      // x + t*NN; batch stride TN
    const float* __restrict__ bias,
    const float* __restrict__ alpha,
    float* __restrict__ out_t) {        // out + t*NN; batch stride TN
  int gid = blockIdx.x * blockDim.x + threadIdx.x;
  int node = gid >> 3;
  int lane = gid & 7;
  if (node >= NN) return;

  int e0 = row_ptr[node];
  int e1 = row_ptr[node + 1];
  int mybase = e0 + lane;
  int rem = e1 - mybase;
  int cnt = rem > 0 ? ((rem + LPN - 1) >> 3) : 0;   // my edge count (stride 8)

  // node-state loads independent of the edge chain — issue early
  float a = alpha[node];
  float bs = bias[node];
  size_t idx = (size_t)node * NB + lane;
  size_t boff = (size_t)lane * TN + node;
  float v = v_old[idx];
  float xv = __builtin_nontemporal_load(&x_t[boff]);

  // prefetch CSR entries (independent, exec-masked per slot)
  int soff[KPRE];
  float wk[KPRE];
#pragma unroll
  for (int k = 0; k < KPRE; ++k) {
    int2 c = (k < cnt) ? csr[mybase + (k << 3)] : make_int2(0, 0);
    soff[k] = c.x;
    wk[k] = __int_as_float(c.y);
  }

  // predicated independent gathers: inactive slots issue NO memory request
  uint4 rv[KPRE];
#pragma unroll
  for (int k = 0; k < KPRE; ++k) {
    if (k < cnt)
      rv[k] = *(const uint4*)((const char*)r_old + soff[k]);
    else
      rv[k] = make_uint4(0, 0, 0, 0);
  }

  float acc[NB];
#pragma unroll
  for (int j = 0; j < NB; ++j) acc[j] = 0.f;

#pragma unroll
  for (int k = 0; k < KPRE; ++k) {
    float w = wk[k];
    acc[0] += w * __uint_as_float(rv[k].x << 16);
    acc[1] += w * __uint_as_float(rv[k].x & 0xffff0000u);
    acc[2] += w * __uint_as_float(rv[k].y << 16);
    acc[3] += w * __uint_as_float(rv[k].y & 0xffff0000u);
    acc[4] += w * __uint_as_float(rv[k].z << 16);
    acc[5] += w * __uint_as_float(rv[k].z & 0xffff0000u);
    acc[6] += w * __uint_as_float(rv[k].w << 16);
    acc[7] += w * __uint_as_float(rv[k].w & 0xffff0000u);
  }

  // overflow edges (deg > 64; essentially never at Poisson(32))
  for (int e = mybase + (KPRE << 3); e < e1; e += LPN) {
    int2 c = csr[e];
    uint4 r8 = *(const uint4*)((const char*)r_old + c.x);
    float w = __int_as_float(c.y);
    acc[0] += w * __uint_as_float(r8.x << 16);
    acc[1] += w * __uint_as_float(r8.x & 0xffff0000u);
    acc[2] += w * __uint_as_float(r8.y << 16);
    acc[3] += w * __uint_as_float(r8.y & 0xffff0000u);
    acc[4] += w * __uint_as_float(r8.z << 16);
    acc[5] += w * __uint_as_float(r8.z & 0xffff0000u);
    acc[6] += w * __uint_as_float(r8.w << 16);
    acc[7] += w * __uint_as_float(r8.w & 0xffff0000u);
  }

  // butterfly reduce across the 8-lane group; lane l ends with valid acc[l]
#pragma unroll
  for (int off = 4; off; off >>= 1) {
#pragma unroll
    for (int j = 0; j < NB; ++j) {
      float t = __shfl_xor(acc[j], off);
      acc[j] = (((lane ^ j) & off) == 0) ? acc[j] + t : acc[j];
    }
  }
  float r = acc[0];
#pragma unroll
  for (int j = 1; j < NB; ++j) r = (lane == j) ? acc[j] : r;

  float vn = v + a * (bs - v + r + xv);
  v_new[idx] = vn;
  __hip_bfloat16 rh = __float2bfloat16(fmaxf(vn, 0.f));
  r_new[idx] = *(ushort*)&rh;
  __builtin_nontemporal_store(vn, &out_t[boff]);
}

// ---------------------------------------------------------------------------

extern "C" void kernel_launch(void* const* d_in, const int* in_sizes, int n_in,
                              void* d_out, int out_size, void* d_ws, size_t ws_size,
                              hipStream_t stream) {
  const float* x        = (const float*)d_in[0];
  const float* bias     = (const float*)d_in[1];
  const float* tc       = (const float*)d_in[2];
  const float* sgn      = (const float*)d_in[3];
  const float* syn_cnt  = (const float*)d_in[4];
  const float* syn_str  = (const float*)d_in[5];
  const int*   src      = (const int*)d_in[6];
  const int*   tgt      = (const int*)d_in[7];
  float* out = (float*)d_out;

  // Workspace carve-out (~19 MB)
  char* p = (char*)d_ws;
  auto take = [&p](size_t bytes) {
    char* r = p;
    p += (bytes + 255) & ~(size_t)255;
    return (void*)r;
  };
  float*  v_a      = (float*)take((size_t)NN * NB * sizeof(float));
  float*  v_b      = (float*)take((size_t)NN * NB * sizeof(float));
  ushort* r_a      = (ushort*)take((size_t)NN * NB * sizeof(ushort));
  ushort* r_b      = (ushort*)take((size_t)NN * NB * sizeof(ushort));
  float*  alpha    = (float*)take((size_t)NN * sizeof(float));
  int*    row_ptr  = (int*)take(((size_t)NN + 1) * sizeof(int));
  int*    cnt      = (int*)take((size_t)NN * sizeof(int));
  int*    cursor   = (int*)take((size_t)NN * sizeof(int));
  int*    escan    = (int*)take((size_t)NN * sizeof(int));
  int*    partials = (int*)take((size_t)SCAN_NB * sizeof(int));
  int2*   csr      = (int2*)take((size_t)NE * sizeof(int2));

  // Build CSR-by-target + node params (once per call)
  init_nodes_kernel<<<(NN + 255) / 256, 256, 0, stream>>>(bias, tc, v_a, r_a, alpha, cnt);
  hist_kernel<<<(NE + 255) / 256, 256, 0, stream>>>(tgt, cnt);
  scan1_kernel<<<SCAN_NB, SCAN_BS, 0, stream>>>(cnt, escan, partials);
  scan2_kernel<<<1, SCAN_BS, 0, stream>>>(partials, row_ptr);
  scan3_kernel<<<SCAN_NB, SCAN_BS, 0, stream>>>(escan, partials, row_ptr, cursor);
  fill_kernel<<<(NE + 255) / 256, 256, 0, stream>>>(src, tgt, sgn, syn_cnt, syn_str,
                                                    cursor, csr);

  // Sequential Euler steps; 8 lanes/node, 400K threads, plain launches.
  const int blocks = (NN * LPN + 255) / 256;
  const float* vin = v_a;
  float* vout = v_b;
  const ushort* rin = r_a;
  ushort* rout = r_b;
  for (int t = 0; t < NT; ++t) {
    step1_kernel<<<blocks, 256, 0, stream>>>(
        row_ptr, csr, vin, rin, vout, rout,
        x + (size_t)t * NN, bias, alpha, out + (size_t)t * NN);
    float* tv = (float*)vin; vin = vout; vout = tv;
    ushort* tr = (ushort*)rin; rin = rout; rout = tr;
  }
}

// Round 7
// 1145.960 us; speedup vs baseline: 4.6786x; 1.0291x over previous
//
#include <hip/hip_runtime.h>
#include <hip/hip_bf16.h>

// Problem constants (Network_29197187678952)
#define NN 50000          // nodes
#define NE 1600000        // edges
#define NB 8              // batch
#define NT 80             // timesteps
#define TN ((size_t)NT * NN)   // stride between batches in x/out: 4,000,000
#define DT_F 0.02f

#define LPN 8             // lanes (threads) per node in the step kernel
#define KPRE 6            // prefetched edges per lane (covers deg <= 48, ~99.7%)

// Bucketed CSR build
#define BKT_SHIFT 11
#define NBKT 25                         // ceil(50000 / 2048)
#define NBKT_PAD 32                     // mod-8-aligned for XCD pinning
#define BKT_CAP 72000                   // mean 65.5K, sigma ~253 -> 17+ sigma
#define ACHUNK 1024                     // edges staged per block-iteration in fillA
#define BPB 64                          // blocks per bucket in fillB

// ---------------------------------------------------------------------------
// Setup kernels (rebuilt every call).
// ---------------------------------------------------------------------------

__global__ void init_nodes_kernel(const float* __restrict__ bias,
                                  const float* __restrict__ tc,
                                  float* __restrict__ v0,
                                  ushort* __restrict__ r0,
                                  float* __restrict__ alpha,
                                  int* __restrict__ cnt,
                                  int* __restrict__ bucket_cursor) {
  int n = blockIdx.x * blockDim.x + threadIdx.x;
  if (n >= NN) return;
  float b = bias[n];
  __hip_bfloat16 rb = __float2bfloat16(fmaxf(b, 0.f));
  ushort rbu = *(ushort*)&rb;
#pragma unroll
  for (int j = 0; j < NB; ++j) {
    v0[(size_t)n * NB + j] = b;
    r0[(size_t)n * NB + j] = rbu;
  }
  alpha[n] = DT_F / fmaxf(tc[n], DT_F);
  cnt[n] = 0;
  if (n < NBKT_PAD) bucket_cursor[n] = 0;
}

// ---- fallback path kernels (used only if ws_size too small) ----
__global__ void hist_kernel(const int* __restrict__ tgt, int* __restrict__ cnt) {
  int e = blockIdx.x * blockDim.x + threadIdx.x;
  if (e >= NE) return;
  atomicAdd(&cnt[tgt[e]], 1);
}

__global__ void fill_kernel(const int* __restrict__ src, const int* __restrict__ tgt,
                            const float* __restrict__ sgn, const float* __restrict__ syn_cnt,
                            const float* __restrict__ syn_str,
                            int* __restrict__ cursor,
                            int2* __restrict__ csr) {
  int e = blockIdx.x * blockDim.x + threadIdx.x;
  if (e >= NE) return;
  int t = tgt[e];
  float w = sgn[e] * syn_cnt[e] * fmaxf(syn_str[e], 0.f);
  int pos = atomicAdd(&cursor[t], 1);
  csr[pos] = make_int2(src[e] * (NB * 2), __float_as_int(w));
}

// ---- fillA: bucketize edges by target-range + fused node histogram ----
// Per 1024-edge chunk: LDS radix-scatter into 25 buckets, block-level global
// reservation, then semi-coalesced copy-out (runs of ~40 8B entries/bucket).
__global__ __launch_bounds__(256) void fillA_kernel(
    const int* __restrict__ src, const int* __restrict__ tgt,
    const float* __restrict__ sgn, const float* __restrict__ syn_cnt,
    const float* __restrict__ syn_str,
    int* __restrict__ node_cnt,            // per-node in-degree (fused hist)
    int* __restrict__ bucket_cursor,       // per-bucket append cursor
    unsigned long long* __restrict__ bkt) { // bucket entry arrays [NBKT][BKT_CAP]
  __shared__ int bcnt[NBKT];
  __shared__ int bbase[NBKT];
  __shared__ int bpos[NBKT + 1];
  __shared__ unsigned long long stage[ACHUNK];
  __shared__ unsigned char stageb[ACHUNK];

  const int tid = threadIdx.x;
  const int base = blockIdx.x * ACHUNK;

  // load this thread's 4 edges (coalesced)
  int b_[4], off_[4];
  unsigned long long ent_[4];
  bool val_[4];
#pragma unroll
  for (int k = 0; k < 4; ++k) {
    int e = base + k * 256 + tid;
    val_[k] = e < NE;
    b_[k] = 0;
    ent_[k] = 0;
    if (val_[k]) {
      int s = src[e];
      int t = tgt[e];
      float w = sgn[e] * syn_cnt[e] * fmaxf(syn_str[e], 0.f);
      atomicAdd(&node_cnt[t], 1);
      b_[k] = t >> BKT_SHIFT;
      unsigned int packed = (unsigned int)s | ((unsigned int)(t & ((1 << BKT_SHIFT) - 1)) << 16);
      ent_[k] = ((unsigned long long)(unsigned int)__float_as_int(w) << 32) | packed;
    }
  }

  if (tid < NBKT) bcnt[tid] = 0;
  __syncthreads();
#pragma unroll
  for (int k = 0; k < 4; ++k)
    if (val_[k]) off_[k] = atomicAdd(&bcnt[b_[k]], 1);
  __syncthreads();
  if (tid == 0) {                       // tiny serial exclusive scan (25 elems)
    int run = 0;
    for (int i = 0; i < NBKT; ++i) { bpos[i] = run; run += bcnt[i]; }
    bpos[NBKT] = run;                   // = total valid in chunk
  }
  __syncthreads();
  if (tid < NBKT) bbase[tid] = atomicAdd(&bucket_cursor[tid], bcnt[tid]);
  // stage entries grouped by bucket
#pragma unroll
  for (int k = 0; k < 4; ++k) {
    if (val_[k]) {
      int slot = bpos[b_[k]] + off_[k];
      stage[slot] = ent_[k];
      stageb[slot] = (unsigned char)b_[k];
    }
  }
  __syncthreads();
  const int tot = bpos[NBKT];
  for (int i = tid; i < tot; i += 256) {
    int bb = stageb[i];
    int dst = bbase[bb] + (i - bpos[bb]);
    if (dst < BKT_CAP)
      bkt[(size_t)bb * BKT_CAP + dst] = stage[i];
  }
}

// ---- fillB: scatter bucket entries into CSR (bucket pinned to one XCD) ----
// blockIdx = j*NBKT_PAD + b  ->  XCD = blockIdx % 8 = b % 8 for all of bucket
// b's blocks; bucket's ~0.5 MB CSR segment stays in that XCD's L2 so the
// random 8B writes accumulate into full lines before writeback.
__global__ __launch_bounds__(256) void fillB_kernel(
    const unsigned long long* __restrict__ bkt,
    const int* __restrict__ bucket_cursor,   // per-bucket counts after fillA
    int* __restrict__ cursor,                // per-node CSR cursor
    int2* __restrict__ csr) {
  const int b = blockIdx.x & (NBKT_PAD - 1);
  if (b >= NBKT) return;
  const int j = blockIdx.x >> 5;             // 0..BPB-1
  const int count = bucket_cursor[b];
  const unsigned long long* mybkt = bkt + (size_t)b * BKT_CAP;
  for (int i = j * 256 + threadIdx.x; i < count; i += BPB * 256) {
    unsigned long long ent = mybkt[i];
    unsigned int packed = (unsigned int)ent;
    int w_bits = (int)(ent >> 32);
    int s = packed & 0xFFFF;
    int t = (b << BKT_SHIFT) + ((packed >> 16) & ((1 << BKT_SHIFT) - 1));
    int pos = atomicAdd(&cursor[t], 1);
    csr[pos] = make_int2(s * (NB * 2), w_bits);
  }
}

// --- hierarchical 3-phase scan over NN counts ---
#define SCAN_BS 256
#define SCAN_NB ((NN + SCAN_BS - 1) / SCAN_BS)   // 196 blocks

__global__ __launch_bounds__(SCAN_BS) void scan1_kernel(
    const int* __restrict__ cnt, int* __restrict__ escan,
    int* __restrict__ partials) {
  __shared__ int buf[2][SCAN_BS];
  const int tid = threadIdx.x;
  const int i = blockIdx.x * SCAN_BS + tid;
  int v = (i < NN) ? cnt[i] : 0;
  int sel = 0;
  buf[0][tid] = v;
  __syncthreads();
#pragma unroll
  for (int off = 1; off < SCAN_BS; off <<= 1) {
    int s = buf[sel][tid];
    if (tid >= off) s += buf[sel][tid - off];
    buf[sel ^ 1][tid] = s;
    sel ^= 1;
    __syncthreads();
  }
  int incl = buf[sel][tid];
  if (i < NN) escan[i] = incl - v;
  if (tid == SCAN_BS - 1) partials[blockIdx.x] = incl;
}

__global__ __launch_bounds__(SCAN_BS) void scan2_kernel(
    int* __restrict__ partials, int* __restrict__ row_ptr) {
  __shared__ int buf[2][SCAN_BS];
  const int tid = threadIdx.x;
  int v = (tid < SCAN_NB) ? partials[tid] : 0;
  int sel = 0;
  buf[0][tid] = v;
  __syncthreads();
#pragma unroll
  for (int off = 1; off < SCAN_BS; off <<= 1) {
    int s = buf[sel][tid];
    if (tid >= off) s += buf[sel][tid - off];
    buf[sel ^ 1][tid] = s;
    sel ^= 1;
    __syncthreads();
  }
  int incl = buf[sel][tid];
  if (tid < SCAN_NB) partials[tid] = incl - v;
  if (tid == SCAN_BS - 1) row_ptr[NN] = incl;
}

__global__ __launch_bounds__(SCAN_BS) void scan3_kernel(
    const int* __restrict__ escan, const int* __restrict__ partials,
    int* __restrict__ row_ptr, int* __restrict__ cursor) {
  const int i = blockIdx.x * SCAN_BS + threadIdx.x;
  if (i >= NN) return;
  int r = escan[i] + partials[blockIdx.x];
  row_ptr[i] = r;
  cursor[i] = r;
}

// ---------------------------------------------------------------------------
// Per-timestep fused kernel (unchanged structure; KPRE=6).
// ---------------------------------------------------------------------------
__global__ __launch_bounds__(256) void step1_kernel(
    const int* __restrict__ row_ptr,
    const int2* __restrict__ csr,
    const float* __restrict__ v_old,
    const ushort* __restrict__ r_old,   // bf16 relu state, node-major (N,8)
    float* __restrict__ v_new,
    ushort* __restrict__ r_new,
    const float* __restrict__ x_t,
    const float* __restrict__ bias,
    const float* __restrict__ alpha,
    float* __restrict__ out_t) {
  int gid = blockIdx.x * blockDim.x + threadIdx.x;
  int node = gid >> 3;
  int lane = gid & 7;
  if (node >= NN) return;

  int e0 = row_ptr[node];
  int e1 = row_ptr[node + 1];
  int mybase = e0 + lane;
  int rem = e1 - mybase;
  int cnt = rem > 0 ? ((rem + LPN - 1) >> 3) : 0;

  float a = alpha[node];
  float bs = bias[node];
  size_t idx = (size_t)node * NB + lane;
  size_t boff = (size_t)lane * TN + node;
  float v = v_old[idx];
  float xv = __builtin_nontemporal_load(&x_t[boff]);

  int soff[KPRE];
  float wk[KPRE];
#pragma unroll
  for (int k = 0; k < KPRE; ++k) {
    int2 c = (k < cnt) ? csr[mybase + (k << 3)] : make_int2(0, 0);
    soff[k] = c.x;
    wk[k] = __int_as_float(c.y);
  }

  uint4 rv[KPRE];
#pragma unroll
  for (int k = 0; k < KPRE; ++k) {
    if (k < cnt)
      rv[k] = *(const uint4*)((const char*)r_old + soff[k]);
    else
      rv[k] = make_uint4(0, 0, 0, 0);
  }

  float acc[NB];
#pragma unroll
  for (int j = 0; j < NB; ++j) acc[j] = 0.f;

#pragma unroll
  for (int k = 0; k < KPRE; ++k) {
    float w = wk[k];
    acc[0] += w * __uint_as_float(rv[k].x << 16);
    acc[1] += w * __uint_as_float(rv[k].x & 0xffff0000u);
    acc[2] += w * __uint_as_float(rv[k].y << 16);
    acc[3] += w * __uint_as_float(rv[k].y & 0xffff0000u);
    acc[4] += w * __uint_as_float(rv[k].z << 16);
    acc[5] += w * __uint_as_float(rv[k].z & 0xffff0000u);
    acc[6] += w * __uint_as_float(rv[k].w << 16);
    acc[7] += w * __uint_as_float(rv[k].w & 0xffff0000u);
  }

  for (int e = mybase + (KPRE << 3); e < e1; e += LPN) {
    int2 c = csr[e];
    uint4 r8 = *(const uint4*)((const char*)r_old + c.x);
    float w = __int_as_float(c.y);
    acc[0] += w * __uint_as_float(r8.x << 16);
    acc[1] += w * __uint_as_float(r8.x & 0xffff0000u);
    acc[2] += w * __uint_as_float(r8.y << 16);
    acc[3] += w * __uint_as_float(r8.y & 0xffff0000u);
    acc[4] += w * __uint_as_float(r8.z << 16);
    acc[5] += w * __uint_as_float(r8.z & 0xffff0000u);
    acc[6] += w * __uint_as_float(r8.w << 16);
    acc[7] += w * __uint_as_float(r8.w & 0xffff0000u);
  }

#pragma unroll
  for (int off = 4; off; off >>= 1) {
#pragma unroll
    for (int j = 0; j < NB; ++j) {
      float t = __shfl_xor(acc[j], off);
      acc[j] = (((lane ^ j) & off) == 0) ? acc[j] + t : acc[j];
    }
  }
  float r = acc[0];
#pragma unroll
  for (int j = 1; j < NB; ++j) r = (lane == j) ? acc[j] : r;

  float vn = v + a * (bs - v + r + xv);
  v_new[idx] = vn;
  __hip_bfloat16 rh = __float2bfloat16(fmaxf(vn, 0.f));
  r_new[idx] = *(ushort*)&rh;
  __builtin_nontemporal_store(vn, &out_t[boff]);
}

// ---------------------------------------------------------------------------

extern "C" void kernel_launch(void* const* d_in, const int* in_sizes, int n_in,
                              void* d_out, int out_size, void* d_ws, size_t ws_size,
                              hipStream_t stream) {
  const float* x        = (const float*)d_in[0];
  const float* bias     = (const float*)d_in[1];
  const float* tc       = (const float*)d_in[2];
  const float* sgn      = (const float*)d_in[3];
  const float* syn_cnt  = (const float*)d_in[4];
  const float* syn_str  = (const float*)d_in[5];
  const int*   src      = (const int*)d_in[6];
  const int*   tgt      = (const int*)d_in[7];
  float* out = (float*)d_out;

  char* p = (char*)d_ws;
  auto take = [&p](size_t bytes) {
    char* r = p;
    p += (bytes + 255) & ~(size_t)255;
    return (void*)r;
  };
  float*  v_a      = (float*)take((size_t)NN * NB * sizeof(float));
  float*  v_b      = (float*)take((size_t)NN * NB * sizeof(float));
  ushort* r_a      = (ushort*)take((size_t)NN * NB * sizeof(ushort));
  ushort* r_b      = (ushort*)take((size_t)NN * NB * sizeof(ushort));
  float*  alpha    = (float*)take((size_t)NN * sizeof(float));
  int*    row_ptr  = (int*)take(((size_t)NN + 1) * sizeof(int));
  int*    cnt      = (int*)take((size_t)NN * sizeof(int));
  int*    cursor   = (int*)take((size_t)NN * sizeof(int));
  int*    escan    = (int*)take((size_t)NN * sizeof(int));
  int*    partials = (int*)take((size_t)SCAN_NB * sizeof(int));
  int*    bcur     = (int*)take((size_t)NBKT_PAD * sizeof(int));
  int2*   csr      = (int2*)take((size_t)NE * sizeof(int2));
  char*   end_base = p;
  unsigned long long* bkt =
      (unsigned long long*)take((size_t)NBKT * BKT_CAP * sizeof(unsigned long long));
  const bool use_bucketed = ((size_t)(p - (char*)d_ws) <= ws_size);
  (void)end_base;

  init_nodes_kernel<<<(NN + 255) / 256, 256, 0, stream>>>(bias, tc, v_a, r_a,
                                                          alpha, cnt, bcur);
  if (use_bucketed) {
    // bucketize (+fused hist) -> scan -> XCD-pinned scatter
    fillA_kernel<<<(NE + ACHUNK - 1) / ACHUNK, 256, 0, stream>>>(
        src, tgt, sgn, syn_cnt, syn_str, cnt, bcur, bkt);
    scan1_kernel<<<SCAN_NB, SCAN_BS, 0, stream>>>(cnt, escan, partials);
    scan2_kernel<<<1, SCAN_BS, 0, stream>>>(partials, row_ptr);
    scan3_kernel<<<SCAN_NB, SCAN_BS, 0, stream>>>(escan, partials, row_ptr, cursor);
    fillB_kernel<<<NBKT_PAD * BPB, 256, 0, stream>>>(bkt, bcur, cursor, csr);
  } else {
    hist_kernel<<<(NE + 255) / 256, 256, 0, stream>>>(tgt, cnt);
    scan1_kernel<<<SCAN_NB, SCAN_BS, 0, stream>>>(cnt, escan, partials);
    scan2_kernel<<<1, SCAN_BS, 0, stream>>>(partials, row_ptr);
    scan3_kernel<<<SCAN_NB, SCAN_BS, 0, stream>>>(escan, partials, row_ptr, cursor);
    fill_kernel<<<(NE + 255) / 256, 256, 0, stream>>>(src, tgt, sgn, syn_cnt,
                                                      syn_str, cursor, csr);
  }

  const int blocks = (NN * LPN + 255) / 256;
  const float* vin = v_a;
  float* vout = v_b;
  const ushort* rin = r_a;
  ushort* rout = r_b;
  for (int t = 0; t < NT; ++t) {
    step1_kernel<<<blocks, 256, 0, stream>>>(
        row_ptr, csr, vin, rin, vout, rout,
        x + (size_t)t * NN, bias, alpha, out + (size_t)t * NN);
    float* tv = (float*)vin; vin = vout; vout = tv;
    ushort* tr = (ushort*)rin; rin = rout; rout = tr;
  }
}